// Round 6
// baseline (316.597 us; speedup 1.0000x reference)
//
#include <hip/hip_runtime.h>
#include <hip/hip_bf16.h>

#define NN 8192
#define KDIM 256
#define FDIM 64
#define SLOPEC 0.2f

// ===== DIAGNOSTIC ROUND: internal x4 repeats (output-invariant) to push our
// kernels past the ~155us fill dispatches into the profile top-5. =====
#define REP_ADJ 4
#define REP_P2  4

typedef __attribute__((ext_vector_type(8))) short bf16x8;
typedef __attribute__((ext_vector_type(4))) float f32x4;

__device__ __forceinline__ unsigned short f2bf(float x) {
    union { float f; unsigned u; } v; v.f = x;
    unsigned r = v.u + 0x7FFFu + ((v.u >> 16) & 1u);
    return (unsigned short)(r >> 16);
}

__device__ __forceinline__ short f2bf_cvt(float x) {
    __hip_bfloat16 b = __float2bfloat16(x);   // RNE; compiler packs pairs
    return __builtin_bit_cast(short, b);
}

__device__ __forceinline__ float wred64(float v) {
    v += __shfl_xor(v, 1);
    v += __shfl_xor(v, 2);
    v += __shfl_xor(v, 4);
    v += __shfl_xor(v, 8);
    v += __shfl_xor(v, 16);
    v += __shfl_xor(v, 32);
    return v;
}

// Phase 1: Wh = h@W (f32 accum); emit whT in MFMA-fragment order:
// window t (32 cols): lane l holds Wh[t*32 + (l>>4)*8 + e][b*16 + (l&15)].
__global__ __launch_bounds__(256) void gat_phase1(
    const float* __restrict__ h, const float* __restrict__ W,
    const float* __restrict__ a, unsigned short* __restrict__ wfrag,
    float* __restrict__ fi, float* __restrict__ fj)
{
    __shared__ unsigned short wht_s[FDIM][20];
    const int tid = threadIdx.x;
    const int f  = tid & 63;
    const int rg = tid >> 6;
    const int i0 = blockIdx.x << 4;

    const float* __restrict__ h0 = h + (size_t)(i0 + rg * 4) * KDIM;
    const float* __restrict__ h1 = h0 + KDIM;
    const float* __restrict__ h2 = h0 + 2 * KDIM;
    const float* __restrict__ h3 = h0 + 3 * KDIM;

    float acc0 = 0.f, acc1 = 0.f, acc2 = 0.f, acc3 = 0.f;
    #pragma unroll 4
    for (int k4 = 0; k4 < KDIM / 4; ++k4) {
        const float4 r0 = *(const float4*)(h0 + k4 * 4);
        const float4 r1 = *(const float4*)(h1 + k4 * 4);
        const float4 r2 = *(const float4*)(h2 + k4 * 4);
        const float4 r3 = *(const float4*)(h3 + k4 * 4);
        const float w0 = W[(k4 * 4 + 0) * FDIM + f];
        const float w1 = W[(k4 * 4 + 1) * FDIM + f];
        const float w2 = W[(k4 * 4 + 2) * FDIM + f];
        const float w3 = W[(k4 * 4 + 3) * FDIM + f];
        acc0 += r0.x * w0 + r0.y * w1 + r0.z * w2 + r0.w * w3;
        acc1 += r1.x * w0 + r1.y * w1 + r1.z * w2 + r1.w * w3;
        acc2 += r2.x * w0 + r2.y * w1 + r2.z * w2 + r2.w * w3;
        acc3 += r3.x * w0 + r3.y * w1 + r3.z * w2 + r3.w * w3;
    }

    const int r0i = rg * 4;
    wht_s[f][r0i + 0] = f2bf(acc0);
    wht_s[f][r0i + 1] = f2bf(acc1);
    wht_s[f][r0i + 2] = f2bf(acc2);
    wht_s[f][r0i + 3] = f2bf(acc3);

    const float aL = a[f];
    const float aR = a[FDIM + f];
    float s;
    s = wred64(acc0 * aL); if (f == 0) fi[i0 + r0i + 0] = s;
    s = wred64(acc1 * aL); if (f == 0) fi[i0 + r0i + 1] = s;
    s = wred64(acc2 * aL); if (f == 0) fi[i0 + r0i + 2] = s;
    s = wred64(acc3 * aL); if (f == 0) fi[i0 + r0i + 3] = s;
    s = wred64(acc0 * aR); if (f == 0) fj[i0 + r0i + 0] = s;
    s = wred64(acc1 * aR); if (f == 0) fj[i0 + r0i + 1] = s;
    s = wred64(acc2 * aR); if (f == 0) fj[i0 + r0i + 2] = s;
    s = wred64(acc3 * aR); if (f == 0) fj[i0 + r0i + 3] = s;

    __syncthreads();
    if (tid < 128) {
        const int li2 = tid & 15;
        const int q2  = (tid >> 4) & 1;
        const int b   = tid >> 5;
        const int t   = i0 >> 5;
        const int hh  = (i0 >> 4) & 1;
        const int feat = b * 16 + li2;
        const ushort4 lo = *(const ushort4*)&wht_s[feat][q2 * 8];
        const ushort4 hi = *(const ushort4*)&wht_s[feat][q2 * 8 + 4];
        const int lg = (hh * 2 + q2) * 16 + li2;
        unsigned short* dst = wfrag + (size_t)t * 2048 + b * 512 + lg * 8;
        *(ushort4*)(dst)     = lo;
        *(ushort4*)(dst + 4) = hi;
    }
}

// Phase 2a: pure adj stream -> row-major bitmask (x REP_ADJ, idempotent).
__global__ __launch_bounds__(256) void gat_adjmask(
    const int* __restrict__ adj, unsigned* __restrict__ mask)
{
    const int tid = threadIdx.x;
    const int l  = tid & 63;
    const int gw = (blockIdx.x << 2) | (tid >> 6);
    const int* __restrict__ row = adj + (size_t)gw * NN;
    unsigned* __restrict__ mrow = mask + (size_t)gw * (NN / 32);

    const int wsel = (l & 7) * 4;
    for (int rep = 0; rep < REP_ADJ; ++rep) {
        #pragma unroll 1
        for (int base = 0; base < 32; base += 8) {
            int4 v[8];
            #pragma unroll
            for (int k = 0; k < 8; ++k)
                v[k] = *(const int4*)(row + (base + k) * 256 + l * 4);
            #pragma unroll
            for (int k = 0; k < 8; ++k) {
                unsigned nib = (unsigned)(v[k].x > 0) | ((unsigned)(v[k].y > 0) << 1)
                             | ((unsigned)(v[k].z > 0) << 2) | ((unsigned)(v[k].w > 0) << 3);
                unsigned part = nib << wsel;
                part |= __shfl_xor(part, 1);
                part |= __shfl_xor(part, 2);
                part |= __shfl_xor(part, 4);
                if ((l & 7) == 0) mrow[(base + k) * 8 + (l >> 3)] = part;
            }
        }
        asm volatile("" ::: "memory");   // keep reps materialized
    }
}

// Phase 2b: 512 thr (8 waves), 16 rows/block (x REP_P2: acc,z scale by REP_P2,
// quotient invariant). Slimmed cvt via __float2bfloat16.
__global__ __launch_bounds__(512, 4) void gat_phase2(
    const unsigned* __restrict__ mask, const unsigned short* __restrict__ wfrag,
    const float* __restrict__ fi, const float* __restrict__ fjg,
    float* __restrict__ out)
{
    __shared__ float fj_s[NN];        // 32 KB; reused as red[] in epilogue
    __shared__ float zred[128];

    const int tid = threadIdx.x;
    const int w  = tid >> 6;
    const int l  = tid & 63;
    const int li = l & 15;
    const int q  = l >> 4;
    const int qo = q * 8;
    const int i0 = blockIdx.x << 4;

    for (int t4 = tid; t4 < NN / 4; t4 += 512)
        ((float4*)fj_s)[t4] = ((const float4*)fjg)[t4];
    __syncthreads();

    const float f_i = fi[i0 + li];
    const unsigned* __restrict__ mrow = mask + (size_t)(i0 + li) * (NN / 32);
    const unsigned short* __restrict__ wf = wfrag + l * 8;

    f32x4 acc0 = {0.f, 0.f, 0.f, 0.f};
    f32x4 acc1 = {0.f, 0.f, 0.f, 0.f};
    f32x4 acc2 = {0.f, 0.f, 0.f, 0.f};
    f32x4 acc3 = {0.f, 0.f, 0.f, 0.f};
    float z = 0.f;

    for (int rep = 0; rep < REP_P2; ++rep) {
        #pragma unroll 4
        for (int tw = w; tw < NN / 32; tw += 8) {
            const int jg = tw * 32 + qo;
            const unsigned mq = mrow[tw] >> qo;
            const float4 fj0 = *(const float4*)(fj_s + jg);
            const float4 fj1 = *(const float4*)(fj_s + jg + 4);
            const unsigned short* wt = wf + (size_t)tw * 2048;
            const bf16x8 b0 = *(const bf16x8*)(wt);
            const bf16x8 b1 = *(const bf16x8*)(wt + 512);
            const bf16x8 b2 = *(const bf16x8*)(wt + 1024);
            const bf16x8 b3 = *(const bf16x8*)(wt + 1536);
            float e0 = f_i + fj0.x; e0 = fmaxf(e0, SLOPEC * e0);
            float e1 = f_i + fj0.y; e1 = fmaxf(e1, SLOPEC * e1);
            float e2 = f_i + fj0.z; e2 = fmaxf(e2, SLOPEC * e2);
            float e3 = f_i + fj0.w; e3 = fmaxf(e3, SLOPEC * e3);
            float e4 = f_i + fj1.x; e4 = fmaxf(e4, SLOPEC * e4);
            float e5 = f_i + fj1.y; e5 = fmaxf(e5, SLOPEC * e5);
            float e6 = f_i + fj1.z; e6 = fmaxf(e6, SLOPEC * e6);
            float e7 = f_i + fj1.w; e7 = fmaxf(e7, SLOPEC * e7);
            const float p0 = (mq &   1u) ? __expf(e0) : 0.f;
            const float p1 = (mq &   2u) ? __expf(e1) : 0.f;
            const float p2 = (mq &   4u) ? __expf(e2) : 0.f;
            const float p3 = (mq &   8u) ? __expf(e3) : 0.f;
            const float p4 = (mq &  16u) ? __expf(e4) : 0.f;
            const float p5 = (mq &  32u) ? __expf(e5) : 0.f;
            const float p6 = (mq &  64u) ? __expf(e6) : 0.f;
            const float p7 = (mq & 128u) ? __expf(e7) : 0.f;
            z += ((p0 + p1) + (p2 + p3)) + ((p4 + p5) + (p6 + p7));
            bf16x8 afrag;
            afrag[0] = f2bf_cvt(p0);
            afrag[1] = f2bf_cvt(p1);
            afrag[2] = f2bf_cvt(p2);
            afrag[3] = f2bf_cvt(p3);
            afrag[4] = f2bf_cvt(p4);
            afrag[5] = f2bf_cvt(p5);
            afrag[6] = f2bf_cvt(p6);
            afrag[7] = f2bf_cvt(p7);
            acc0 = __builtin_amdgcn_mfma_f32_16x16x32_bf16(afrag, b0, acc0, 0, 0, 0);
            acc1 = __builtin_amdgcn_mfma_f32_16x16x32_bf16(afrag, b1, acc1, 0, 0, 0);
            acc2 = __builtin_amdgcn_mfma_f32_16x16x32_bf16(afrag, b2, acc2, 0, 0, 0);
            acc3 = __builtin_amdgcn_mfma_f32_16x16x32_bf16(afrag, b3, acc3, 0, 0, 0);
        }
        asm volatile("" ::: "memory");
    }

    __syncthreads();
    float* red = fj_s;
    #pragma unroll
    for (int r = 0; r < 4; ++r) {
        red[(w * 16 + q * 4 + r) * 64 + 0 * 16 + li] = acc0[r];
        red[(w * 16 + q * 4 + r) * 64 + 1 * 16 + li] = acc1[r];
        red[(w * 16 + q * 4 + r) * 64 + 2 * 16 + li] = acc2[r];
        red[(w * 16 + q * 4 + r) * 64 + 3 * 16 + li] = acc3[r];
    }
    z += __shfl_xor(z, 16);
    z += __shfl_xor(z, 32);
    if (q == 0) zred[w * 16 + li] = z;
    __syncthreads();

    const int f  = tid & 63;
    const int ig = tid >> 6;
    #pragma unroll
    for (int cc = 0; cc < 2; ++cc) {
        const int i = cc * 8 + ig;
        const float v = ((red[(0 * 16 + i) * 64 + f] + red[(1 * 16 + i) * 64 + f])
                       + (red[(2 * 16 + i) * 64 + f] + red[(3 * 16 + i) * 64 + f]))
                      + ((red[(4 * 16 + i) * 64 + f] + red[(5 * 16 + i) * 64 + f])
                       + (red[(6 * 16 + i) * 64 + f] + red[(7 * 16 + i) * 64 + f]));
        const float zz = ((zred[0 * 16 + i] + zred[1 * 16 + i]) + (zred[2 * 16 + i] + zred[3 * 16 + i]))
                       + ((zred[4 * 16 + i] + zred[5 * 16 + i]) + (zred[6 * 16 + i] + zred[7 * 16 + i]));
        out[(size_t)(i0 + i) * FDIM + f] = v / zz;
    }
}

extern "C" void kernel_launch(void* const* d_in, const int* in_sizes, int n_in,
                              void* d_out, int out_size, void* d_ws, size_t ws_size,
                              hipStream_t stream) {
    const float* h   = (const float*)d_in[0];
    const int*   adj = (const int*)d_in[1];
    const float* W   = (const float*)d_in[2];
    const float* a   = (const float*)d_in[3];
    float* out = (float*)d_out;

    unsigned short* wfrag = (unsigned short*)d_ws;                      // 1 MB @ 0
    float* fi = (float*)((char*)d_ws + (size_t)NN * FDIM * 2);          // 32 KB @ 1MB
    float* fj = fi + NN;                                                // 32 KB
    unsigned* mask = (unsigned*)((char*)d_ws + (2u << 20));             // 8 MB @ 2MB

    gat_phase1<<<NN / 16, 256, 0, stream>>>(h, W, a, wfrag, fi, fj);
    gat_adjmask<<<NN / 4, 256, 0, stream>>>(adj, mask);
    gat_phase2<<<NN / 16, 512, 0, stream>>>(mask, wfrag, fi, fj, out);
}

// Round 7
// 130.171 us; speedup vs baseline: 2.4322x; 2.4322x over previous
//
#include <hip/hip_runtime.h>
#include <hip/hip_fp16.h>

#define NN 8192
#define KDIM 256
#define FDIM 64

typedef __attribute__((ext_vector_type(8))) _Float16 f16x8;
typedef __attribute__((ext_vector_type(4))) float f32x4;

union H2U { __half2 h; unsigned u; };
union HU  { __half h; unsigned short u; };

__device__ __forceinline__ unsigned h2u(__half2 h) { H2U x; x.h = h; return x.u; }

// packed fp16 mul/max via asm (deterministic vs header availability)
__device__ __forceinline__ unsigned pkmul(unsigned a, unsigned b) {
    unsigned d; asm("v_pk_mul_f16 %0, %1, %2" : "=v"(d) : "v"(a), "v"(b)); return d;
}
__device__ __forceinline__ unsigned pkmax(unsigned a, unsigned b) {
    unsigned d; asm("v_pk_max_f16 %0, %1, %2" : "=v"(d) : "v"(a), "v"(b)); return d;
}

__device__ __forceinline__ float wred64(float v) {
    v += __shfl_xor(v, 1);
    v += __shfl_xor(v, 2);
    v += __shfl_xor(v, 4);
    v += __shfl_xor(v, 8);
    v += __shfl_xor(v, 16);
    v += __shfl_xor(v, 32);
    return v;
}

// Phase 1: Wh = h@W (f32 accum); emit Wh^T in MFMA-fragment order as fp16:
// window t (32 cols): lane l holds Wh[t*32 + (l>>4)*8 + e][b*16 + (l&15)].
__global__ __launch_bounds__(256) void gat_phase1(
    const float* __restrict__ h, const float* __restrict__ W,
    const float* __restrict__ a, unsigned short* __restrict__ wfrag,
    float* __restrict__ fi, float* __restrict__ fj)
{
    __shared__ unsigned short wht_s[FDIM][20];
    const int tid = threadIdx.x;
    const int f  = tid & 63;
    const int rg = tid >> 6;
    const int i0 = blockIdx.x << 4;

    const float* __restrict__ h0 = h + (size_t)(i0 + rg * 4) * KDIM;
    const float* __restrict__ h1 = h0 + KDIM;
    const float* __restrict__ h2 = h0 + 2 * KDIM;
    const float* __restrict__ h3 = h0 + 3 * KDIM;

    float acc0 = 0.f, acc1 = 0.f, acc2 = 0.f, acc3 = 0.f;
    #pragma unroll 4
    for (int k4 = 0; k4 < KDIM / 4; ++k4) {
        const float4 r0 = *(const float4*)(h0 + k4 * 4);
        const float4 r1 = *(const float4*)(h1 + k4 * 4);
        const float4 r2 = *(const float4*)(h2 + k4 * 4);
        const float4 r3 = *(const float4*)(h3 + k4 * 4);
        const float w0 = W[(k4 * 4 + 0) * FDIM + f];
        const float w1 = W[(k4 * 4 + 1) * FDIM + f];
        const float w2 = W[(k4 * 4 + 2) * FDIM + f];
        const float w3 = W[(k4 * 4 + 3) * FDIM + f];
        acc0 += r0.x * w0 + r0.y * w1 + r0.z * w2 + r0.w * w3;
        acc1 += r1.x * w0 + r1.y * w1 + r1.z * w2 + r1.w * w3;
        acc2 += r2.x * w0 + r2.y * w1 + r2.z * w2 + r2.w * w3;
        acc3 += r3.x * w0 + r3.y * w1 + r3.z * w2 + r3.w * w3;
    }

    HU c0; c0.h = __float2half(acc0);
    HU c1; c1.h = __float2half(acc1);
    HU c2; c2.h = __float2half(acc2);
    HU c3; c3.h = __float2half(acc3);
    const int r0i = rg * 4;
    wht_s[f][r0i + 0] = c0.u;
    wht_s[f][r0i + 1] = c1.u;
    wht_s[f][r0i + 2] = c2.u;
    wht_s[f][r0i + 3] = c3.u;

    const float aL = a[f];
    const float aR = a[FDIM + f];
    float s;
    s = wred64(acc0 * aL); if (f == 0) fi[i0 + r0i + 0] = s;
    s = wred64(acc1 * aL); if (f == 0) fi[i0 + r0i + 1] = s;
    s = wred64(acc2 * aL); if (f == 0) fi[i0 + r0i + 2] = s;
    s = wred64(acc3 * aL); if (f == 0) fi[i0 + r0i + 3] = s;
    s = wred64(acc0 * aR); if (f == 0) fj[i0 + r0i + 0] = s;
    s = wred64(acc1 * aR); if (f == 0) fj[i0 + r0i + 1] = s;
    s = wred64(acc2 * aR); if (f == 0) fj[i0 + r0i + 2] = s;
    s = wred64(acc3 * aR); if (f == 0) fj[i0 + r0i + 3] = s;

    __syncthreads();
    if (tid < 128) {
        const int li2 = tid & 15;
        const int q2  = (tid >> 4) & 1;
        const int b   = tid >> 5;
        const int t   = i0 >> 5;
        const int hh  = (i0 >> 4) & 1;
        const int feat = b * 16 + li2;
        const ushort4 lo = *(const ushort4*)&wht_s[feat][q2 * 8];
        const ushort4 hi = *(const ushort4*)&wht_s[feat][q2 * 8 + 4];
        const int lg = (hh * 2 + q2) * 16 + li2;
        unsigned short* dst = wfrag + (size_t)t * 2048 + b * 512 + lg * 8;
        *(ushort4*)(dst)     = lo;
        *(ushort4*)(dst + 4) = hi;
    }
}

// Phase 2a: adj -> byte mask (0x00/0xFF), CHIP-ADDRESS-ORDER streaming.
// Grid-stride slices: all 524288 threads cover one contiguous 8 MB slice per step,
// 8 slices in flight -> dense DRAM footprint (row-buffer friendly).
__global__ __launch_bounds__(256) void gat_adjmask(
    const int4* __restrict__ adj4, unsigned* __restrict__ bm32)
{
    const int gtid = (blockIdx.x << 8) | threadIdx.x;
    const int TOT = 2048 * 256;                 // threads in grid
    #pragma unroll 1
    for (int s0 = 0; s0 < 32; s0 += 8) {
        int4 v[8];
        #pragma unroll
        for (int k = 0; k < 8; ++k)
            v[k] = adj4[(size_t)(s0 + k) * TOT + gtid];
        #pragma unroll
        for (int k = 0; k < 8; ++k) {
            const unsigned b = (v[k].x > 0 ? 0x000000FFu : 0u)
                             | (v[k].y > 0 ? 0x0000FF00u : 0u)
                             | (v[k].z > 0 ? 0x00FF0000u : 0u)
                             | (v[k].w > 0 ? 0xFF000000u : 0u);
            bm32[(size_t)(s0 + k) * TOT + gtid] = b;
        }
    }
}

// Phase 2b: 512 thr (8 waves), 16 rows/block.
// p = exp(lrelu(fi+fj)) = max(E1i*E1j, E2i*E2j); packed fp16 math, byte-mask AND,
// z via 5th MFMA with B = ones. No exp/cvt in the inner loop.
__global__ __launch_bounds__(512, 4) void gat_phase2(
    const unsigned char* __restrict__ bm, const unsigned short* __restrict__ wfrag,
    const float* __restrict__ fi, const float* __restrict__ fjg,
    float* __restrict__ out)
{
    __shared__ unsigned Ebuf[NN];     // E1 pairs [0,NN/2) + E2 pairs [NN/2,NN): 32 KB; reused as red[]
    __shared__ float zred[128];

    const int tid = threadIdx.x;
    const int w  = tid >> 6;   // 0..7
    const int l  = tid & 63;
    const int li = l & 15;     // MFMA A/C row group
    const int q  = l >> 4;     // k-quarter
    const int qo = q * 8;
    const int i0 = blockIdx.x << 4;

    unsigned* E1p = Ebuf;
    unsigned* E2p = Ebuf + NN / 2;
    for (int t = tid; t < NN / 2; t += 512) {
        const float2 f2 = ((const float2*)fjg)[t];
        E1p[t] = h2u(__floats2half2_rn(__expf(f2.x), __expf(f2.y)));
        E2p[t] = h2u(__floats2half2_rn(__expf(0.2f * f2.x), __expf(0.2f * f2.y)));
    }
    __syncthreads();

    const float fiv = fi[i0 + li];
    const unsigned e1i2 = h2u(__floats2half2_rn(__expf(fiv), __expf(fiv)));
    const unsigned e2i2 = h2u(__floats2half2_rn(__expf(0.2f * fiv), __expf(0.2f * fiv)));

    const unsigned char*  __restrict__ brow = bm + (size_t)(i0 + li) * NN;
    const unsigned short* __restrict__ wf   = wfrag + l * 8;

    f32x4 acc0 = {0.f, 0.f, 0.f, 0.f};
    f32x4 acc1 = {0.f, 0.f, 0.f, 0.f};
    f32x4 acc2 = {0.f, 0.f, 0.f, 0.f};
    f32x4 acc3 = {0.f, 0.f, 0.f, 0.f};
    f32x4 accz = {0.f, 0.f, 0.f, 0.f};
    const f16x8 ones = { (_Float16)1.f, (_Float16)1.f, (_Float16)1.f, (_Float16)1.f,
                         (_Float16)1.f, (_Float16)1.f, (_Float16)1.f, (_Float16)1.f };

    #pragma unroll 4
    for (int tw = w; tw < NN / 32; tw += 8) {
        const int jg = tw * 32 + qo;
        const uint2 mw  = *(const uint2*)(brow + jg);
        const uint4 e1w = *(const uint4*)(E1p + (jg >> 1));
        const uint4 e2w = *(const uint4*)(E2p + (jg >> 1));
        const unsigned short* wt = wf + (size_t)tw * 2048;
        const f16x8 b0 = *(const f16x8*)(wt);
        const f16x8 b1 = *(const f16x8*)(wt + 512);
        const f16x8 b2 = *(const f16x8*)(wt + 1024);
        const f16x8 b3 = *(const f16x8*)(wt + 1536);

        // byte mask -> halfword-pair masks (v_perm): [b,b] per fp16 half
        const unsigned mm0 = __builtin_amdgcn_perm(0u, mw.x, 0x01010000u);
        const unsigned mm1 = __builtin_amdgcn_perm(0u, mw.x, 0x03030202u);
        const unsigned mm2 = __builtin_amdgcn_perm(0u, mw.y, 0x01010000u);
        const unsigned mm3 = __builtin_amdgcn_perm(0u, mw.y, 0x03030202u);

        union { unsigned u[4]; f16x8 v; } af;
        af.u[0] = pkmax(pkmul(e1i2, e1w.x), pkmul(e2i2, e2w.x)) & mm0;
        af.u[1] = pkmax(pkmul(e1i2, e1w.y), pkmul(e2i2, e2w.y)) & mm1;
        af.u[2] = pkmax(pkmul(e1i2, e1w.z), pkmul(e2i2, e2w.z)) & mm2;
        af.u[3] = pkmax(pkmul(e1i2, e1w.w), pkmul(e2i2, e2w.w)) & mm3;

        acc0 = __builtin_amdgcn_mfma_f32_16x16x32_f16(af.v, b0, acc0, 0, 0, 0);
        acc1 = __builtin_amdgcn_mfma_f32_16x16x32_f16(af.v, b1, acc1, 0, 0, 0);
        acc2 = __builtin_amdgcn_mfma_f32_16x16x32_f16(af.v, b2, acc2, 0, 0, 0);
        acc3 = __builtin_amdgcn_mfma_f32_16x16x32_f16(af.v, b3, acc3, 0, 0, 0);
        accz = __builtin_amdgcn_mfma_f32_16x16x32_f16(af.v, ones, accz, 0, 0, 0);
    }

    // epilogue: cross-wave reduce + normalize (red reuses Ebuf)
    __syncthreads();
    float* red = (float*)Ebuf;
    #pragma unroll
    for (int r = 0; r < 4; ++r) {
        red[(w * 16 + q * 4 + r) * 64 + 0 * 16 + li] = acc0[r];
        red[(w * 16 + q * 4 + r) * 64 + 1 * 16 + li] = acc1[r];
        red[(w * 16 + q * 4 + r) * 64 + 2 * 16 + li] = acc2[r];
        red[(w * 16 + q * 4 + r) * 64 + 3 * 16 + li] = acc3[r];
    }
    if (li == 0) {                      // lanes 0,16,32,48 hold z for rows q*4+r (all cols equal)
        #pragma unroll
        for (int r = 0; r < 4; ++r)
            zred[w * 16 + q * 4 + r] = accz[r];
    }
    __syncthreads();

    const int f  = tid & 63;
    const int ig = tid >> 6;
    #pragma unroll
    for (int cc = 0; cc < 2; ++cc) {
        const int i = cc * 8 + ig;
        const float v = ((red[(0 * 16 + i) * 64 + f] + red[(1 * 16 + i) * 64 + f])
                       + (red[(2 * 16 + i) * 64 + f] + red[(3 * 16 + i) * 64 + f]))
                      + ((red[(4 * 16 + i) * 64 + f] + red[(5 * 16 + i) * 64 + f])
                       + (red[(6 * 16 + i) * 64 + f] + red[(7 * 16 + i) * 64 + f]));
        const float zz = ((zred[0 * 16 + i] + zred[1 * 16 + i]) + (zred[2 * 16 + i] + zred[3 * 16 + i]))
                       + ((zred[4 * 16 + i] + zred[5 * 16 + i]) + (zred[6 * 16 + i] + zred[7 * 16 + i]));
        out[(size_t)(i0 + i) * FDIM + f] = v / zz;
    }
}

extern "C" void kernel_launch(void* const* d_in, const int* in_sizes, int n_in,
                              void* d_out, int out_size, void* d_ws, size_t ws_size,
                              hipStream_t stream) {
    const float* h   = (const float*)d_in[0];
    const int*   adj = (const int*)d_in[1];
    const float* W   = (const float*)d_in[2];
    const float* a   = (const float*)d_in[3];
    float* out = (float*)d_out;

    unsigned short* wfrag = (unsigned short*)d_ws;                      // 1 MB @ 0 (fp16 fragment-order)
    float* fi = (float*)((char*)d_ws + (size_t)NN * FDIM * 2);          // 32 KB @ 1MB
    float* fj = fi + NN;                                                // 32 KB
    unsigned char* bm = (unsigned char*)d_ws + (2u << 20);              // 8 MB byte-mask @ 2MB

    gat_phase1<<<NN / 16, 256, 0, stream>>>(h, W, a, wfrag, fi, fj);
    gat_adjmask<<<2048, 256, 0, stream>>>((const int4*)adj, (unsigned*)bm);
    gat_phase2<<<NN / 16, 512, 0, stream>>>(bm, wfrag, fi, fj, out);
}